// Round 1
// baseline (309.832 us; speedup 1.0000x reference)
//
#include <hip/hip_runtime.h>
#include <math.h>

#define HD 768
#define NL 3
#define BB 64
#define SS 512

__device__ __forceinline__ float lse3(float x, float y, float z) {
    float m = fmaxf(fmaxf(x, y), z);
    return m + __logf(__expf(x - m) + __expf(y - m) + __expf(z - m));
}

// One wave (64 lanes) per token. Lane l loads float4 chunks l, l+64, l+128 of
// the 768-float hidden row, accumulates 3 dot products, wave-reduces.
// Output layout: em[(s*B + b)*3 + j]  (i.e. [S,B,3]) so the CRF kernel's
// per-batch threads read coalesced.
__global__ __launch_bounds__(256) void emis_kernel(
    const float* __restrict__ hidden, const float* __restrict__ W,
    const float* __restrict__ bias, float* __restrict__ em) {
    int gid  = blockIdx.x * blockDim.x + threadIdx.x;
    int wave = gid >> 6;
    int lane = threadIdx.x & 63;
    int BS = BB * SS;
    if (wave >= BS) return;
    const float4* h4 = (const float4*)(hidden + (size_t)wave * HD);
    float a0 = 0.f, a1 = 0.f, a2 = 0.f;
#pragma unroll
    for (int i = 0; i < 3; ++i) {
        int k4 = lane + 64 * i;          // float4 index within the row
        float4 v = h4[k4];
        int k = k4 * 4;
        a0 = fmaf(v.x, W[(k + 0) * 3 + 0], a0);
        a1 = fmaf(v.x, W[(k + 0) * 3 + 1], a1);
        a2 = fmaf(v.x, W[(k + 0) * 3 + 2], a2);
        a0 = fmaf(v.y, W[(k + 1) * 3 + 0], a0);
        a1 = fmaf(v.y, W[(k + 1) * 3 + 1], a1);
        a2 = fmaf(v.y, W[(k + 1) * 3 + 2], a2);
        a0 = fmaf(v.z, W[(k + 2) * 3 + 0], a0);
        a1 = fmaf(v.z, W[(k + 2) * 3 + 1], a1);
        a2 = fmaf(v.z, W[(k + 2) * 3 + 2], a2);
        a0 = fmaf(v.w, W[(k + 3) * 3 + 0], a0);
        a1 = fmaf(v.w, W[(k + 3) * 3 + 1], a1);
        a2 = fmaf(v.w, W[(k + 3) * 3 + 2], a2);
    }
#pragma unroll
    for (int off = 32; off; off >>= 1) {
        a0 += __shfl_down(a0, off);
        a1 += __shfl_down(a1, off);
        a2 += __shfl_down(a2, off);
    }
    if (lane == 0) {
        int b = wave >> 9;           // wave / SS
        int s = wave & (SS - 1);     // wave % SS
        float* o = em + ((size_t)s * BB + b) * NL;
        o[0] = a0 + bias[0];
        o[1] = a1 + bias[1];
        o[2] = a2 + bias[2];
    }
}

// One wave, thread b = batch b. Sequential over S; L=3 fully unrolled in regs.
__global__ __launch_bounds__(64) void crf_kernel(
    const float* __restrict__ em,          // [S,B,3]
    const int* __restrict__ mask,          // [B,S]
    const int* __restrict__ labels,        // [B,S]
    const float* __restrict__ startT, const float* __restrict__ endT,
    const float* __restrict__ trans, float* __restrict__ out) {
    int b = threadIdx.x;
    float T[9];
#pragma unroll
    for (int i = 0; i < 9; ++i) T[i] = trans[i];
    float end0 = endT[0], end1 = endT[1], end2 = endT[2];

    float contrib = 0.f;
    if (b < BB) {
        const int* tg = labels + b * SS;
        const int* mk = mask + b * SS;
        int t0 = tg[0]; if (t0 < 0) t0 = 0;
        float e00 = em[b * NL + 0], e01 = em[b * NL + 1], e02 = em[b * NL + 2];
        float score = startT[t0] + (t0 == 0 ? e00 : (t0 == 1 ? e01 : e02));
        int prev = t0, last = t0;
        float A0 = startT[0] + e00;
        float A1 = startT[1] + e01;
        float A2 = startT[2] + e02;
        for (int s = 1; s < SS; ++s) {
            const float* es = em + ((size_t)s * BB + b) * NL;
            float v0 = es[0], v1 = es[1], v2 = es[2];
            int t = tg[s]; if (t < 0) t = 0;
            int m = mk[s];
            float ev = (t == 0 ? v0 : (t == 1 ? v1 : v2));
            if (m) {
                score += ev + T[prev * 3 + t];
                last = t;
            }
            prev = t;
            float n0 = lse3(A0 + T[0], A1 + T[3], A2 + T[6]) + v0;
            float n1 = lse3(A0 + T[1], A1 + T[4], A2 + T[7]) + v1;
            float n2 = lse3(A0 + T[2], A1 + T[5], A2 + T[8]) + v2;
            if (m) { A0 = n0; A1 = n1; A2 = n2; }
        }
        score += (last == 0 ? end0 : (last == 1 ? end1 : end2));
        float logZ = lse3(A0 + end0, A1 + end1, A2 + end2);
        contrib = logZ - score;
    }
#pragma unroll
    for (int off = 32; off; off >>= 1) contrib += __shfl_down(contrib, off);
    if (b == 0) out[0] = contrib * (1.0f / BB);
}

extern "C" void kernel_launch(void* const* d_in, const int* in_sizes, int n_in,
                              void* d_out, int out_size, void* d_ws, size_t ws_size,
                              hipStream_t stream) {
    const float* hidden = (const float*)d_in[0];
    const float* W      = (const float*)d_in[1];
    const float* bias   = (const float*)d_in[2];
    const float* startT = (const float*)d_in[3];
    const float* endT   = (const float*)d_in[4];
    const float* trans  = (const float*)d_in[5];
    const int*   mask   = (const int*)d_in[6];
    const int*   labels = (const int*)d_in[7];
    float* out = (float*)d_out;

    float* em = (float*)d_ws;  // B*S*3 floats = 384 KiB

    int BS = BB * SS;                       // 32768 tokens, one wave each
    int blocks = BS / 4;                    // 4 waves per 256-thread block
    emis_kernel<<<blocks, 256, 0, stream>>>(hidden, W, bias, em);
    crf_kernel<<<1, 64, 0, stream>>>(em, mask, labels, startT, endT, trans, out);
}

// Round 2
// 42.925 us; speedup vs baseline: 7.2180x; 7.2180x over previous
//
#include <hip/hip_runtime.h>
#include <math.h>

#define HD 768
#define NL 3
#define BB 64
#define SS 512
#define NEG (-1e30f)

__device__ __forceinline__ float lse3(float x, float y, float z) {
    float m = fmaxf(fmaxf(x, y), z);
    return m + __logf(__expf(x - m) + __expf(y - m) + __expf(z - m));
}

// One wave (64 lanes) per token. Lane l loads float4 chunks l, l+64, l+128 of
// the 768-float hidden row, accumulates 3 dot products, wave-reduces.
// Output layout: em[(s*B + b)*3 + j]  (i.e. [S,B,3]).
__global__ __launch_bounds__(256) void emis_kernel(
    const float* __restrict__ hidden, const float* __restrict__ W,
    const float* __restrict__ bias, float* __restrict__ em) {
    int gid  = blockIdx.x * blockDim.x + threadIdx.x;
    int wave = gid >> 6;
    int lane = threadIdx.x & 63;
    int BS = BB * SS;
    if (wave >= BS) return;
    const float4* h4 = (const float4*)(hidden + (size_t)wave * HD);
    float a0 = 0.f, a1 = 0.f, a2 = 0.f;
#pragma unroll
    for (int i = 0; i < 3; ++i) {
        int k4 = lane + 64 * i;          // float4 index within the row
        float4 v = h4[k4];
        int k = k4 * 4;
        a0 = fmaf(v.x, W[(k + 0) * 3 + 0], a0);
        a1 = fmaf(v.x, W[(k + 0) * 3 + 1], a1);
        a2 = fmaf(v.x, W[(k + 0) * 3 + 2], a2);
        a0 = fmaf(v.y, W[(k + 1) * 3 + 0], a0);
        a1 = fmaf(v.y, W[(k + 1) * 3 + 1], a1);
        a2 = fmaf(v.y, W[(k + 1) * 3 + 2], a2);
        a0 = fmaf(v.z, W[(k + 2) * 3 + 0], a0);
        a1 = fmaf(v.z, W[(k + 2) * 3 + 1], a1);
        a2 = fmaf(v.z, W[(k + 2) * 3 + 2], a2);
        a0 = fmaf(v.w, W[(k + 3) * 3 + 0], a0);
        a1 = fmaf(v.w, W[(k + 3) * 3 + 1], a1);
        a2 = fmaf(v.w, W[(k + 3) * 3 + 2], a2);
    }
#pragma unroll
    for (int off = 32; off; off >>= 1) {
        a0 += __shfl_down(a0, off);
        a1 += __shfl_down(a1, off);
        a2 += __shfl_down(a2, off);
    }
    if (lane == 0) {
        int b = wave >> 9;           // wave / SS
        int s = wave & (SS - 1);     // wave % SS
        float* o = em + ((size_t)s * BB + b) * NL;
        o[0] = a0 + bias[0];
        o[1] = a1 + bias[1];
        o[2] = a2 + bias[2];
    }
}

// One wave per batch (blockIdx.x = b). Lane l owns steps [8l, 8l+8) (lane 0:
// steps 1..7; step 0 is the alpha0 init). Each lane builds the 3x3 semiring
// matrix product of its chunk, then a shfl_down tree (increasing offsets —
// non-commutative op) gives lane 0 the full product M_1⊗...⊗M_511.
// Gold score terms and last-tag are parallel-reduced the same way.
__global__ __launch_bounds__(64) void crf_scan_kernel(
    const float* __restrict__ em,          // [S,B,3]
    const int* __restrict__ mask,          // [B,S]
    const int* __restrict__ labels,        // [B,S]
    const float* __restrict__ startT, const float* __restrict__ endT,
    const float* __restrict__ trans, float* __restrict__ part) {
    int b = blockIdx.x;
    int l = threadIdx.x;

    float T[3][3];
#pragma unroll
    for (int i = 0; i < 3; ++i)
#pragma unroll
        for (int j = 0; j < 3; ++j) T[i][j] = trans[i * 3 + j];

    const int* tg = labels + b * SS;
    const int* mk = mask + b * SS;

    int s0   = l * 8;
    int sbeg = (s0 < 1) ? 1 : s0;
    int send = s0 + 8;

    // semiring identity
    float P[3][3];
#pragma unroll
    for (int i = 0; i < 3; ++i)
#pragma unroll
        for (int j = 0; j < 3; ++j) P[i][j] = (i == j) ? 0.f : NEG;

    float gold = 0.f;
    int last_s = -1, last_t = 0;

    for (int s = sbeg; s < send; ++s) {
        const float* es = em + ((size_t)s * BB + b) * NL;
        float e0 = es[0], e1 = es[1], e2 = es[2];
        int m  = mk[s];
        int tp = tg[s - 1]; if (tp < 0) tp = 0;
        int t  = tg[s];     if (t  < 0) t  = 0;
        if (m) {
            float ev = (t == 0 ? e0 : (t == 1 ? e1 : e2));
            gold += ev + T[tp][t];
            last_s = s; last_t = t;
            float N[3][3];
#pragma unroll
            for (int i = 0; i < 3; ++i) {
                float a0 = P[i][0], a1 = P[i][1], a2 = P[i][2];
                N[i][0] = lse3(a0 + T[0][0], a1 + T[1][0], a2 + T[2][0]) + e0;
                N[i][1] = lse3(a0 + T[0][1], a1 + T[1][1], a2 + T[2][1]) + e1;
                N[i][2] = lse3(a0 + T[0][2], a1 + T[1][2], a2 + T[2][2]) + e2;
            }
#pragma unroll
            for (int i = 0; i < 3; ++i) {
                P[i][0] = N[i][0]; P[i][1] = N[i][1]; P[i][2] = N[i][2];
            }
        }
    }

    // tree combine: offsets MUST increase for the non-commutative product.
#pragma unroll
    for (int off = 1; off < 64; off <<= 1) {
        float Bm[3][3];
#pragma unroll
        for (int i = 0; i < 3; ++i)
#pragma unroll
            for (int j = 0; j < 3; ++j) Bm[i][j] = __shfl_down(P[i][j], off);
        float N[3][3];
#pragma unroll
        for (int i = 0; i < 3; ++i) {
            float a0 = P[i][0], a1 = P[i][1], a2 = P[i][2];
#pragma unroll
            for (int j = 0; j < 3; ++j)
                N[i][j] = lse3(a0 + Bm[0][j], a1 + Bm[1][j], a2 + Bm[2][j]);
        }
#pragma unroll
        for (int i = 0; i < 3; ++i)
#pragma unroll
            for (int j = 0; j < 3; ++j) P[i][j] = N[i][j];

        gold += __shfl_down(gold, off);
        int os = __shfl_down(last_s, off);
        int ot = __shfl_down(last_t, off);
        if (os > last_s) { last_s = os; last_t = ot; }
    }

    if (l == 0) {
        int t0 = tg[0]; if (t0 < 0) t0 = 0;
        float e00 = em[b * NL + 0], e01 = em[b * NL + 1], e02 = em[b * NL + 2];
        float a0 = startT[0] + e00, a1 = startT[1] + e01, a2 = startT[2] + e02;
        float f0 = lse3(a0 + P[0][0], a1 + P[1][0], a2 + P[2][0]);
        float f1 = lse3(a0 + P[0][1], a1 + P[1][1], a2 + P[2][1]);
        float f2 = lse3(a0 + P[0][2], a1 + P[1][2], a2 + P[2][2]);
        float logZ = lse3(f0 + endT[0], f1 + endT[1], f2 + endT[2]);
        float sc0 = startT[t0] + (t0 == 0 ? e00 : (t0 == 1 ? e01 : e02));
        if (last_s < 0) last_t = t0;     // no masked step beyond 0
        float score = sc0 + gold + endT[last_t];
        part[b] = logZ - score;
    }
}

__global__ __launch_bounds__(64) void mean_kernel(
    const float* __restrict__ part, float* __restrict__ out) {
    float v = part[threadIdx.x];
#pragma unroll
    for (int off = 32; off; off >>= 1) v += __shfl_down(v, off);
    if (threadIdx.x == 0) out[0] = v * (1.0f / BB);
}

extern "C" void kernel_launch(void* const* d_in, const int* in_sizes, int n_in,
                              void* d_out, int out_size, void* d_ws, size_t ws_size,
                              hipStream_t stream) {
    const float* hidden = (const float*)d_in[0];
    const float* W      = (const float*)d_in[1];
    const float* bias   = (const float*)d_in[2];
    const float* startT = (const float*)d_in[3];
    const float* endT   = (const float*)d_in[4];
    const float* trans  = (const float*)d_in[5];
    const int*   mask   = (const int*)d_in[6];
    const int*   labels = (const int*)d_in[7];
    float* out = (float*)d_out;

    float* em   = (float*)d_ws;                 // B*S*3 floats = 384 KiB
    float* part = em + (size_t)BB * SS * NL;    // 64 floats

    int BS = BB * SS;                           // 32768 tokens, one wave each
    int blocks = BS / 4;                        // 4 waves per 256-thread block
    emis_kernel<<<blocks, 256, 0, stream>>>(hidden, W, bias, em);
    crf_scan_kernel<<<BB, 64, 0, stream>>>(em, mask, labels, startT, endT,
                                           trans, part);
    mean_kernel<<<1, 64, 0, stream>>>(part, out);
}

// Round 3
// 39.857 us; speedup vs baseline: 7.7735x; 1.0770x over previous
//
#include <hip/hip_runtime.h>
#include <math.h>

#define HD 768
#define NL 3
#define BB 64
#define SS 512
#define NEG (-1e30f)

__device__ __forceinline__ float lse3(float x, float y, float z) {
    float m = fmaxf(fmaxf(x, y), z);
    return m + __logf(__expf(x - m) + __expf(y - m) + __expf(z - m));
}

// One wave (64 lanes) per token. Lane l loads float4 chunks l, l+64, l+128 of
// the 768-float hidden row, accumulates 3 dot products, wave-reduces.
// Output layout: em[(b*S + s)*3 + j]  (i.e. [B,S,3]) so the CRF kernel's
// per-lane 8-step chunks are contiguous (coalesced float4 loads).
__global__ __launch_bounds__(256) void emis_kernel(
    const float* __restrict__ hidden, const float* __restrict__ W,
    const float* __restrict__ bias, float* __restrict__ em,
    float* __restrict__ out) {
    if (blockIdx.x == 0 && threadIdx.x == 0) out[0] = 0.f;  // init for atomics
    int gid  = blockIdx.x * blockDim.x + threadIdx.x;
    int wave = gid >> 6;
    int lane = threadIdx.x & 63;
    int BS = BB * SS;
    if (wave >= BS) return;
    const float4* h4 = (const float4*)(hidden + (size_t)wave * HD);
    float a0 = 0.f, a1 = 0.f, a2 = 0.f;
#pragma unroll
    for (int i = 0; i < 3; ++i) {
        int k4 = lane + 64 * i;          // float4 index within the row
        float4 v = h4[k4];
        int k = k4 * 4;
        a0 = fmaf(v.x, W[(k + 0) * 3 + 0], a0);
        a1 = fmaf(v.x, W[(k + 0) * 3 + 1], a1);
        a2 = fmaf(v.x, W[(k + 0) * 3 + 2], a2);
        a0 = fmaf(v.y, W[(k + 1) * 3 + 0], a0);
        a1 = fmaf(v.y, W[(k + 1) * 3 + 1], a1);
        a2 = fmaf(v.y, W[(k + 1) * 3 + 2], a2);
        a0 = fmaf(v.z, W[(k + 2) * 3 + 0], a0);
        a1 = fmaf(v.z, W[(k + 2) * 3 + 1], a1);
        a2 = fmaf(v.z, W[(k + 2) * 3 + 2], a2);
        a0 = fmaf(v.w, W[(k + 3) * 3 + 0], a0);
        a1 = fmaf(v.w, W[(k + 3) * 3 + 1], a1);
        a2 = fmaf(v.w, W[(k + 3) * 3 + 2], a2);
    }
#pragma unroll
    for (int off = 32; off; off >>= 1) {
        a0 += __shfl_down(a0, off);
        a1 += __shfl_down(a1, off);
        a2 += __shfl_down(a2, off);
    }
    if (lane == 0) {
        int b = wave >> 9;           // wave / SS
        int s = wave & (SS - 1);     // wave % SS
        float* o = em + ((size_t)b * SS + s) * NL;
        o[0] = a0 + bias[0];
        o[1] = a1 + bias[1];
        o[2] = a2 + bias[2];
    }
}

// One wave per batch (blockIdx.x = b). Lane l owns steps [8l, 8l+8) (step 0 is
// the alpha0 init, excluded by predicate). All loads coalesced+hoisted:
// 6 float4 of emissions, 2 int4 labels, 2 int4 mask per lane. Each lane builds
// its chunk's 3x3 semiring matrix; shfl_down tree (increasing offsets —
// non-commutative) combines. Gold score / last-tag reduced alongside.
__global__ __launch_bounds__(64) void crf_scan_kernel(
    const float* __restrict__ em,          // [B,S,3]
    const int* __restrict__ mask,          // [B,S]
    const int* __restrict__ labels,        // [B,S]
    const float* __restrict__ startT, const float* __restrict__ endT,
    const float* __restrict__ trans, float* __restrict__ out) {
    int b = blockIdx.x;
    int l = threadIdx.x;

    float T[3][3];
#pragma unroll
    for (int i = 0; i < 3; ++i)
#pragma unroll
        for (int j = 0; j < 3; ++j) T[i][j] = trans[i * 3 + j];

    const float* emb = em + (size_t)b * SS * NL;
    const int*   tg  = labels + b * SS;
    const int*   mk  = mask + b * SS;
    int s0 = l * 8;

    // hoisted coalesced loads
    float4 E[6];
    const float4* ep = (const float4*)(emb + (size_t)s0 * NL);
#pragma unroll
    for (int i = 0; i < 6; ++i) E[i] = ep[i];
    float f[24];
#pragma unroll
    for (int i = 0; i < 6; ++i) {
        f[i * 4 + 0] = E[i].x; f[i * 4 + 1] = E[i].y;
        f[i * 4 + 2] = E[i].z; f[i * 4 + 3] = E[i].w;
    }
    int4 ta = ((const int4*)(tg + s0))[0];
    int4 tb = ((const int4*)(tg + s0))[1];
    int4 ma = ((const int4*)(mk + s0))[0];
    int4 mb = ((const int4*)(mk + s0))[1];
    int tgs[8] = {ta.x, ta.y, ta.z, ta.w, tb.x, tb.y, tb.z, tb.w};
    int mks[8] = {ma.x, ma.y, ma.z, ma.w, mb.x, mb.y, mb.z, mb.w};
    int prev = (l > 0) ? tg[s0 - 1] : 0;
    if (prev < 0) prev = 0;

    float P[3][3];
    bool first = true;
    float gold = 0.f;
    int last_s = -1, last_t = 0;

#pragma unroll
    for (int k = 0; k < 8; ++k) {
        int s = s0 + k;
        float e0 = f[k * 3 + 0], e1 = f[k * 3 + 1], e2 = f[k * 3 + 2];
        int t = tgs[k]; if (t < 0) t = 0;
        bool active = (s > 0) && (mks[k] != 0);
        if (active) {
            float ev = (t == 0 ? e0 : (t == 1 ? e1 : e2));
            gold += ev + T[prev][t];
            last_s = s; last_t = t;
            if (first) {
                first = false;
#pragma unroll
                for (int i = 0; i < 3; ++i) {
                    P[i][0] = T[i][0] + e0;
                    P[i][1] = T[i][1] + e1;
                    P[i][2] = T[i][2] + e2;
                }
            } else {
                float N[3][3];
#pragma unroll
                for (int i = 0; i < 3; ++i) {
                    float a0 = P[i][0], a1 = P[i][1], a2 = P[i][2];
                    N[i][0] = lse3(a0 + T[0][0], a1 + T[1][0], a2 + T[2][0]) + e0;
                    N[i][1] = lse3(a0 + T[0][1], a1 + T[1][1], a2 + T[2][1]) + e1;
                    N[i][2] = lse3(a0 + T[0][2], a1 + T[1][2], a2 + T[2][2]) + e2;
                }
#pragma unroll
                for (int i = 0; i < 3; ++i) {
                    P[i][0] = N[i][0]; P[i][1] = N[i][1]; P[i][2] = N[i][2];
                }
            }
        }
        prev = t;
    }
    if (first) {  // fully-masked chunk: identity
#pragma unroll
        for (int i = 0; i < 3; ++i)
#pragma unroll
            for (int j = 0; j < 3; ++j) P[i][j] = (i == j) ? 0.f : NEG;
    }

    // tree combine: offsets MUST increase for the non-commutative product.
#pragma unroll
    for (int off = 1; off < 64; off <<= 1) {
        float Bm[3][3];
#pragma unroll
        for (int i = 0; i < 3; ++i)
#pragma unroll
            for (int j = 0; j < 3; ++j) Bm[i][j] = __shfl_down(P[i][j], off);
        float N[3][3];
#pragma unroll
        for (int i = 0; i < 3; ++i) {
            float a0 = P[i][0], a1 = P[i][1], a2 = P[i][2];
#pragma unroll
            for (int j = 0; j < 3; ++j)
                N[i][j] = lse3(a0 + Bm[0][j], a1 + Bm[1][j], a2 + Bm[2][j]);
        }
#pragma unroll
        for (int i = 0; i < 3; ++i)
#pragma unroll
            for (int j = 0; j < 3; ++j) P[i][j] = N[i][j];

        gold += __shfl_down(gold, off);
        int os = __shfl_down(last_s, off);
        int ot = __shfl_down(last_t, off);
        if (os > last_s) { last_s = os; last_t = ot; }
    }

    if (l == 0) {
        int t0 = tgs[0]; if (t0 < 0) t0 = 0;
        float e00 = f[0], e01 = f[1], e02 = f[2];
        float a0 = startT[0] + e00, a1 = startT[1] + e01, a2 = startT[2] + e02;
        float f0 = lse3(a0 + P[0][0], a1 + P[1][0], a2 + P[2][0]);
        float f1 = lse3(a0 + P[0][1], a1 + P[1][1], a2 + P[2][1]);
        float f2 = lse3(a0 + P[0][2], a1 + P[1][2], a2 + P[2][2]);
        float logZ = lse3(f0 + endT[0], f1 + endT[1], f2 + endT[2]);
        float sc0 = startT[t0] + (t0 == 0 ? e00 : (t0 == 1 ? e01 : e02));
        if (last_s < 0) last_t = t0;     // no masked step beyond 0
        float score = sc0 + gold + endT[last_t];
        atomicAdd(out, (logZ - score) * (1.0f / BB));
    }
}

extern "C" void kernel_launch(void* const* d_in, const int* in_sizes, int n_in,
                              void* d_out, int out_size, void* d_ws, size_t ws_size,
                              hipStream_t stream) {
    const float* hidden = (const float*)d_in[0];
    const float* W      = (const float*)d_in[1];
    const float* bias   = (const float*)d_in[2];
    const float* startT = (const float*)d_in[3];
    const float* endT   = (const float*)d_in[4];
    const float* trans  = (const float*)d_in[5];
    const int*   mask   = (const int*)d_in[6];
    const int*   labels = (const int*)d_in[7];
    float* out = (float*)d_out;

    float* em = (float*)d_ws;                   // B*S*3 floats = 384 KiB

    int BS = BB * SS;                           // 32768 tokens, one wave each
    int blocks = BS / 4;                        // 4 waves per 256-thread block
    emis_kernel<<<blocks, 256, 0, stream>>>(hidden, W, bias, em, out);
    crf_scan_kernel<<<BB, 64, 0, stream>>>(em, mask, labels, startT, endT,
                                           trans, out);
}